// Round 1
// baseline (541.320 us; speedup 1.0000x reference)
//
#include <hip/hip_runtime.h>
#include <hip/hip_bf16.h>

// VectorQuantizer on MI355X — R8:
//  (a) cooperative coalesced fp64 refine (same 8-candidate set, 4 lanes/token
//      each cover a 16-dim slice; shfl-reduce partials) — removes the
//      per-lane-divergent 64-line gathers that stalled the L1/TA pipe.
//  (b) dw segment-sum fused into vq_main epilogue via direct f32 atomics
//      (same atomic count as the old sorted vq_seg, minus vq_scan/vq_scatter/
//      vq_seg kernels and the 32MB z re-read).
// Inputs (fp32): z[NT,64], codebook[K,64], cluster_size[K], ema_w[K,64]
// d_out (fp32): quantized[NT*64] | indices[NT] | loss[1] | new_codebook[K*64] |
//   new_cluster_size[K] | new_ema_w[K*64]
// ws dwords: cnt[K] | dwacc[K*64] | cnormp[K] | loss | n

#define DECAY 0.99f
#define OMD   0.01f
#define EPSV  1e-5f
#define BIASF 192.0f    // folded into MFMA acc init: score' = 192 + z.c - |c|^2/2 > 0

typedef __attribute__((ext_vector_type(8))) __bf16 bf16x8;
typedef __attribute__((ext_vector_type(4))) float  float4v;

static __device__ __forceinline__ unsigned short bfbits(float f) {
    __bf16 h = (__bf16)f;
    return __builtin_bit_cast(unsigned short, h);
}
static __device__ __forceinline__ bf16x8 cvt8(float4v a, float4v b) {
    bf16x8 r;
    r[0] = (__bf16)a[0]; r[1] = (__bf16)a[1]; r[2] = (__bf16)a[2]; r[3] = (__bf16)a[3];
    r[4] = (__bf16)b[0]; r[5] = (__bf16)b[1]; r[6] = (__bf16)b[2]; r[7] = (__bf16)b[3];
    return r;
}

// key low 8 bits = per-lane candidate number iter = (c<<6)|(t<<2)|r
static __device__ __forceinline__ int dec_idx(unsigned key, int quad) {
    int iter = key & 255;
    return ((iter >> 6) << 8) + (((iter >> 2) & 15) << 4) + (quad << 2) + (iter & 3);
}

__global__ void vq_prep(const float* __restrict__ cb,
                        float* __restrict__ wsf, int* __restrict__ wsi,
                        int K, int NT) {
    const int KD = K * 64;
    int t = blockIdx.x * 256 + threadIdx.x;      // grid covers K*64
    if (t < KD) wsf[K + t] = 0.f;                // dwacc zero-init
    if (t < K) {
        wsi[t] = 0;                               // cnt
        const float4v* cp = (const float4v*)(cb + (size_t)t * 64);
        float s = 0.f;
        #pragma unroll
        for (int i = 0; i < 16; ++i) {
            float4v v = cp[i];
            s += v[0] * v[0] + v[1] * v[1] + v[2] * v[2] + v[3] * v[3];
        }
        wsf[K + KD + t] = BIASF - 0.5f * s;       // cnormp
    }
    if (t == 0) wsf[2 * K + KD] = 0.f;            // loss
}

// 512 threads = 8 waves; 256 tokens/block (32/wave); codebook bf16 in LDS.
__launch_bounds__(512)
__global__ void vq_main(const float* __restrict__ z,
                        const float* __restrict__ cb,
                        float* __restrict__ wsf, int* __restrict__ wsi,
                        float* __restrict__ out,
                        int NT, int K) {
    __shared__ __align__(16) unsigned short cbs[256 * 72];   // 36 KB
    __shared__ float cns[256];
    __shared__ int hist[1024];

    const int tid  = threadIdx.x;
    const int lane = tid & 63;
    const int wave = tid >> 6;
    const int col  = lane & 15;
    const int quad = lane >> 4;
    const int wtok0 = blockIdx.x * 256 + wave * 32;
    const int KD = K * 64;
    const float* cnormp = wsf + (size_t)K + KD;
    float* lossp = wsf + (size_t)2 * K + KD;
    float* dwacc = wsf + K;
    const bool smallK = (K <= 1024);

    for (int i = tid; i < 1024; i += 512) hist[i] = 0;

    bf16x8 bf0[2], bf1[2];
    #pragma unroll
    for (int g = 0; g < 2; ++g) {
        int tok = wtok0 + g * 16 + col;
        if (tok >= NT) tok = NT - 1;
        const float* zp = z + (size_t)tok * 64 + quad * 8;
        float4v f0 = *(const float4v*)(zp);
        float4v f1 = *(const float4v*)(zp + 4);
        float4v f2 = *(const float4v*)(zp + 32);
        float4v f3 = *(const float4v*)(zp + 36);
        bf0[g] = cvt8(f0, f1);
        bf1[g] = cvt8(f2, f3);
    }

    unsigned k1[2] = { 0u, 0u }, k2[2] = { 0u, 0u };
    const unsigned kmask = 0xFFFFFF00u;
    const int nchunk = (K + 255) >> 8;

    for (int c = 0; c < nchunk; ++c) {
        #pragma unroll
        for (int i = 0; i < 8; ++i) {
            int f4 = (i * 512 + tid) * 4;
            int row = f4 >> 6, d = f4 & 63;
            int code = c * 256 + row;
            uint2 p;
            if (code < K) {
                float4v v = *(const float4v*)(cb + (size_t)code * 64 + d);
                p.x = (unsigned int)bfbits(v[0]) | ((unsigned int)bfbits(v[1]) << 16);
                p.y = (unsigned int)bfbits(v[2]) | ((unsigned int)bfbits(v[3]) << 16);
            } else { p.x = 0u; p.y = 0u; }
            *(uint2*)(&cbs[row * 72 + d]) = p;
        }
        if (tid < 256) {
            int code = c * 256 + tid;
            cns[tid] = (code < K) ? cnormp[code] : 0.0f;
        }
        __syncthreads();

        #pragma unroll 4
        for (int t = 0; t < 16; ++t) {
            const unsigned short* arow = cbs + (t * 16 + col) * 72;
            bf16x8 a0 = *(const bf16x8*)(arow + quad * 8);
            bf16x8 a1 = *(const bf16x8*)(arow + 32 + quad * 8);
            float4v cni = *(const float4v*)(cns + t * 16 + quad * 4);
            const int iterbase = (c << 6) | (t << 2);
            #pragma unroll
            for (int g = 0; g < 2; ++g) {
                float4v acc = cni;              // = BIAS - |c|^2/2
                acc = __builtin_amdgcn_mfma_f32_16x16x32_bf16(a0, bf0[g], acc, 0, 0, 0);
                acc = __builtin_amdgcn_mfma_f32_16x16x32_bf16(a1, bf1[g], acc, 0, 0, 0);
                #pragma unroll
                for (int r = 0; r < 4; ++r) {
                    unsigned kb = (__float_as_uint(acc[r]) & kmask) | (unsigned)(iterbase + r);
                    unsigned lo = k2[g] > kb ? k2[g] : kb;
                    k2[g] = k1[g] < lo ? k1[g] : lo;
                    k1[g] = k1[g] > kb ? k1[g] : kb;
                }
            }
        }
        __syncthreads();
    }

    // Cooperative exact refine: the 4 quad-lanes of each token jointly rerank
    // the token's 8 candidates (top-2 from each quad) in fp64. Each lane loads
    // only the 16-dim slice [quad*16, quad*16+16) of z and of each candidate
    // row -> 4 lanes cover a row contiguously (coalesced), vs the old per-lane
    // full-row divergent gather.
    int ibst[2];
    #pragma unroll
    for (int g = 0; g < 2; ++g) {
        int tok = wtok0 + g * 16 + col;
        if (tok >= NT) tok = NT - 1;
        int ia = dec_idx(k1[g], quad);
        int ib = dec_idx(k2[g], quad);
        int cand[8];
        #pragma unroll
        for (int q = 0; q < 4; ++q) {
            cand[2 * q]     = __shfl(ia, q * 16 + col, 64);
            cand[2 * q + 1] = __shfl(ib, q * 16 + col, 64);
        }
        const float* zr = z + (size_t)tok * 64 + quad * 16;
        float4v zv0 = *(const float4v*)(zr);
        float4v zv1 = *(const float4v*)(zr + 4);
        float4v zv2 = *(const float4v*)(zr + 8);
        float4v zv3 = *(const float4v*)(zr + 12);
        double ps[8];
        #pragma unroll
        for (int s = 0; s < 8; ++s) {
            int cc = (cand[s] < K) ? cand[s] : 0;
            const float* cr = cb + (size_t)cc * 64 + quad * 16;
            float4v c0 = *(const float4v*)(cr);
            float4v c1 = *(const float4v*)(cr + 4);
            float4v c2 = *(const float4v*)(cr + 8);
            float4v c3 = *(const float4v*)(cr + 12);
            double a = 0.0;
            #pragma unroll
            for (int j = 0; j < 4; ++j) {
                double e0 = (double)zv0[j] - (double)c0[j];
                double e1 = (double)zv1[j] - (double)c1[j];
                double e2 = (double)zv2[j] - (double)c2[j];
                double e3 = (double)zv3[j] - (double)c3[j];
                a = fma(e0, e0, a); a = fma(e1, e1, a);
                a = fma(e2, e2, a); a = fma(e3, e3, a);
            }
            ps[s] = (cand[s] < K) ? a : 1.0e300;
        }
        #pragma unroll
        for (int s = 0; s < 8; ++s) {
            ps[s] += __shfl_xor(ps[s], 16, 64);
            ps[s] += __shfl_xor(ps[s], 32, 64);
        }
        double bs = ps[0]; int bi = cand[0];
        #pragma unroll
        for (int s = 1; s < 8; ++s) {
            if (ps[s] < bs || (ps[s] == bs && cand[s] < bi)) { bs = ps[s]; bi = cand[s]; }
        }
        ibst[g] = bi;
    }

    const size_t off_idx = (size_t)NT * 64;

    if (lane < 32) {
        int tk = wtok0 + lane;
        if (tk < NT) {
            int ib = (lane < 16) ? ibst[0] : ibst[1];
            out[off_idx + tk] = (float)ib;
            if (smallK) atomicAdd(&hist[ib], 1);
            else        atomicAdd(&wsi[ib], 1);
        }
    }

    // Epilogue: quantized write + commitment loss + fused dw accumulation.
    float lsum = 0.f;
    #pragma unroll
    for (int i = 0; i < 8; ++i) {
        int tw  = i * 4 + quad;
        int g   = i >> 2;
        int idx = __shfl(ibst[g], tw & 15, 64);
        int token = wtok0 + tw;
        if (token < NT) {
            int d4 = col * 4;
            float4v zf = *(const float4v*)(z  + (size_t)token * 64 + d4);
            float4v qf = *(const float4v*)(cb + (size_t)idx   * 64 + d4);
            *(float4v*)(out + (size_t)token * 64 + d4) = qf;
            float* dwp = dwacc + (size_t)idx * 64 + d4;
            atomicAdd(dwp + 0, OMD * zf[0]);
            atomicAdd(dwp + 1, OMD * zf[1]);
            atomicAdd(dwp + 2, OMD * zf[2]);
            atomicAdd(dwp + 3, OMD * zf[3]);
            float e0 = zf[0] - qf[0], e1 = zf[1] - qf[1];
            float e2 = zf[2] - qf[2], e3 = zf[3] - qf[3];
            lsum += e0 * e0 + e1 * e1 + e2 * e2 + e3 * e3;
        }
    }
    #pragma unroll
    for (int off = 1; off < 64; off <<= 1) lsum += __shfl_xor(lsum, off, 64);
    if (lane == 0) atomicAdd(lossp, lsum);

    __syncthreads();
    if (smallK) {
        for (int k = tid; k < K; k += 512) {
            int c = hist[k];
            if (c) atomicAdd(&wsi[k], c);
        }
    }
}

// Single block: n = sum(DECAY*cs + OMD*cnt), loss normalize.
__global__ void vq_nsum(const float* __restrict__ cs,
                        float* __restrict__ wsf, const int* __restrict__ wsi,
                        float* __restrict__ out, int NT, int K) {
    __shared__ float red[16];
    const int tid = threadIdx.x;
    const int KD = K * 64;
    float part = 0.f;
    for (int k = tid; k < K; k += 1024)
        part += DECAY * cs[k] + OMD * (float)wsi[k];
    #pragma unroll
    for (int off = 1; off < 64; off <<= 1) part += __shfl_xor(part, off, 64);
    if ((tid & 63) == 0) red[tid >> 6] = part;
    __syncthreads();
    if (tid == 0) {
        float nn = 0.f;
        #pragma unroll
        for (int i = 0; i < 16; ++i) nn += red[i];
        wsf[2 * K + KD + 1] = nn;                                 // n
        out[(size_t)NT * 64 + NT] = wsf[2 * K + KD] / ((float)NT * 64.0f);
    }
}

// Final: combine accumulators -> new_ema_w, new_codebook, new_cluster_size.
__global__ void vq_final(const float* __restrict__ cs,
                         const float* __restrict__ ema,
                         const float* __restrict__ wsf,
                         const int* __restrict__ wsi,
                         float* __restrict__ out, int NT, int K) {
    const int KD = K * 64;
    int t = blockIdx.x * 256 + threadIdx.x;
    if (t >= KD) return;
    const int k = t >> 6;
    const float n = wsf[2 * K + KD + 1];
    const float dw = DECAY * ema[t] + wsf[K + t];
    const float ncs = DECAY * cs[k] + OMD * (float)wsi[k];
    const float csn = (ncs + EPSV) / (n + (float)K * EPSV) * n;
    const size_t off_cb  = (size_t)NT * 64 + NT + 1;
    const size_t off_cs  = off_cb + (size_t)KD;
    const size_t off_ema = off_cs + K;
    out[off_cb  + t] = dw / csn;
    out[off_ema + t] = dw;
    if ((t & 63) == 0) out[off_cs + k] = ncs;
}

extern "C" void kernel_launch(void* const* d_in, const int* in_sizes, int n_in,
                              void* d_out, int out_size, void* d_ws, size_t ws_size,
                              hipStream_t stream) {
    const float* z   = (const float*)d_in[0];
    const float* cb  = (const float*)d_in[1];
    const float* cs  = (const float*)d_in[2];
    const float* ema = (const float*)d_in[3];
    float* out = (float*)d_out;
    float* wsf = (float*)d_ws;
    int*   wsi = (int*)d_ws;

    const int NT = in_sizes[0] / 64;
    const int K  = in_sizes[2];
    const int KD = K * 64;

    vq_prep<<<(KD + 255) / 256, 256, 0, stream>>>(cb, wsf, wsi, K, NT);
    vq_main<<<(NT + 255) / 256, 512, 0, stream>>>(z, cb, wsf, wsi, out, NT, K);
    vq_nsum<<<1, 1024, 0, stream>>>(cs, wsf, wsi, out, NT, K);
    vq_final<<<(KD + 255) / 256, 256, 0, stream>>>(cs, ema, wsf, wsi, out, NT, K);
}

// Round 2
// 430.495 us; speedup vs baseline: 1.2574x; 1.2574x over previous
//
#include <hip/hip_runtime.h>
#include <hip/hip_bf16.h>

// VectorQuantizer on MI355X — R9:
//  (a) cooperative coalesced fp64 refine (kept from R8; same candidate set as
//      R7, 4 lanes/token each cover a 16-dim slice; shfl-reduce partials).
//  (b) dw via owner-computes reduction: 256 blocks each own K/256 codes with a
//      private LDS accumulator; scan idx[], ballot hits, 64-lane cooperative
//      row add. ZERO global atomics (R8's 8.4M scattered atomics caused
//      +131MB WRITE_SIZE and 3.4x slowdown). Replaces R7's scan/scatter/seg.
// Inputs (fp32): z[NT,64], codebook[K,64], cluster_size[K], ema_w[K,64]
// d_out (fp32): quantized[NT*64] | indices[NT] | loss[1] | new_codebook[K*64] |
//   new_cluster_size[K] | new_ema_w[K*64]
// ws dwords: cnt[K] | dwacc[K*64] | cnormp[K] | loss | n

#define DECAY 0.99f
#define OMD   0.01f
#define EPSV  1e-5f
#define BIASF 192.0f    // folded into MFMA acc init: score' = 192 + z.c - |c|^2/2 > 0

typedef __attribute__((ext_vector_type(8))) __bf16 bf16x8;
typedef __attribute__((ext_vector_type(4))) float  float4v;

static __device__ __forceinline__ unsigned short bfbits(float f) {
    __bf16 h = (__bf16)f;
    return __builtin_bit_cast(unsigned short, h);
}
static __device__ __forceinline__ bf16x8 cvt8(float4v a, float4v b) {
    bf16x8 r;
    r[0] = (__bf16)a[0]; r[1] = (__bf16)a[1]; r[2] = (__bf16)a[2]; r[3] = (__bf16)a[3];
    r[4] = (__bf16)b[0]; r[5] = (__bf16)b[1]; r[6] = (__bf16)b[2]; r[7] = (__bf16)b[3];
    return r;
}

// key low 8 bits = per-lane candidate number iter = (c<<6)|(t<<2)|r
static __device__ __forceinline__ int dec_idx(unsigned key, int quad) {
    int iter = key & 255;
    return ((iter >> 6) << 8) + (((iter >> 2) & 15) << 4) + (quad << 2) + (iter & 3);
}

__global__ void vq_prep(const float* __restrict__ cb,
                        float* __restrict__ wsf, int* __restrict__ wsi,
                        int K, int NT) {
    const int KD = K * 64;
    int t = blockIdx.x * 256 + threadIdx.x;
    if (t < K) {
        wsi[t] = 0;                               // cnt
        const float4v* cp = (const float4v*)(cb + (size_t)t * 64);
        float s = 0.f;
        #pragma unroll
        for (int i = 0; i < 16; ++i) {
            float4v v = cp[i];
            s += v[0] * v[0] + v[1] * v[1] + v[2] * v[2] + v[3] * v[3];
        }
        wsf[K + KD + t] = BIASF - 0.5f * s;       // cnormp
    }
    if (t == 0) wsf[2 * K + KD] = 0.f;            // loss
}

// 512 threads = 8 waves; 256 tokens/block (32/wave); codebook bf16 in LDS.
__launch_bounds__(512)
__global__ void vq_main(const float* __restrict__ z,
                        const float* __restrict__ cb,
                        float* __restrict__ wsf, int* __restrict__ wsi,
                        float* __restrict__ out,
                        int NT, int K) {
    __shared__ __align__(16) unsigned short cbs[256 * 72];   // 36 KB
    __shared__ float cns[256];
    __shared__ int hist[1024];

    const int tid  = threadIdx.x;
    const int lane = tid & 63;
    const int wave = tid >> 6;
    const int col  = lane & 15;
    const int quad = lane >> 4;
    const int wtok0 = blockIdx.x * 256 + wave * 32;
    const int KD = K * 64;
    const float* cnormp = wsf + (size_t)K + KD;
    float* lossp = wsf + (size_t)2 * K + KD;
    const bool smallK = (K <= 1024);

    for (int i = tid; i < 1024; i += 512) hist[i] = 0;

    bf16x8 bf0[2], bf1[2];
    #pragma unroll
    for (int g = 0; g < 2; ++g) {
        int tok = wtok0 + g * 16 + col;
        if (tok >= NT) tok = NT - 1;
        const float* zp = z + (size_t)tok * 64 + quad * 8;
        float4v f0 = *(const float4v*)(zp);
        float4v f1 = *(const float4v*)(zp + 4);
        float4v f2 = *(const float4v*)(zp + 32);
        float4v f3 = *(const float4v*)(zp + 36);
        bf0[g] = cvt8(f0, f1);
        bf1[g] = cvt8(f2, f3);
    }

    unsigned k1[2] = { 0u, 0u }, k2[2] = { 0u, 0u };
    const unsigned kmask = 0xFFFFFF00u;
    const int nchunk = (K + 255) >> 8;

    for (int c = 0; c < nchunk; ++c) {
        #pragma unroll
        for (int i = 0; i < 8; ++i) {
            int f4 = (i * 512 + tid) * 4;
            int row = f4 >> 6, d = f4 & 63;
            int code = c * 256 + row;
            uint2 p;
            if (code < K) {
                float4v v = *(const float4v*)(cb + (size_t)code * 64 + d);
                p.x = (unsigned int)bfbits(v[0]) | ((unsigned int)bfbits(v[1]) << 16);
                p.y = (unsigned int)bfbits(v[2]) | ((unsigned int)bfbits(v[3]) << 16);
            } else { p.x = 0u; p.y = 0u; }
            *(uint2*)(&cbs[row * 72 + d]) = p;
        }
        if (tid < 256) {
            int code = c * 256 + tid;
            cns[tid] = (code < K) ? cnormp[code] : 0.0f;
        }
        __syncthreads();

        #pragma unroll 4
        for (int t = 0; t < 16; ++t) {
            const unsigned short* arow = cbs + (t * 16 + col) * 72;
            bf16x8 a0 = *(const bf16x8*)(arow + quad * 8);
            bf16x8 a1 = *(const bf16x8*)(arow + 32 + quad * 8);
            float4v cni = *(const float4v*)(cns + t * 16 + quad * 4);
            const int iterbase = (c << 6) | (t << 2);
            #pragma unroll
            for (int g = 0; g < 2; ++g) {
                float4v acc = cni;              // = BIAS - |c|^2/2
                acc = __builtin_amdgcn_mfma_f32_16x16x32_bf16(a0, bf0[g], acc, 0, 0, 0);
                acc = __builtin_amdgcn_mfma_f32_16x16x32_bf16(a1, bf1[g], acc, 0, 0, 0);
                #pragma unroll
                for (int r = 0; r < 4; ++r) {
                    unsigned kb = (__float_as_uint(acc[r]) & kmask) | (unsigned)(iterbase + r);
                    unsigned lo = k2[g] > kb ? k2[g] : kb;
                    k2[g] = k1[g] < lo ? k1[g] : lo;
                    k1[g] = k1[g] > kb ? k1[g] : kb;
                }
            }
        }
        __syncthreads();
    }

    // Cooperative exact refine: the 4 quad-lanes of each token jointly rerank
    // the token's 8 candidates (top-2 from each quad) in fp64. Each lane loads
    // only the 16-dim slice [quad*16, quad*16+16) of z and of each candidate
    // row -> coalesced, vs the old per-lane full-row divergent gather.
    int ibst[2];
    #pragma unroll
    for (int g = 0; g < 2; ++g) {
        int tok = wtok0 + g * 16 + col;
        if (tok >= NT) tok = NT - 1;
        int ia = dec_idx(k1[g], quad);
        int ib = dec_idx(k2[g], quad);
        int cand[8];
        #pragma unroll
        for (int q = 0; q < 4; ++q) {
            cand[2 * q]     = __shfl(ia, q * 16 + col, 64);
            cand[2 * q + 1] = __shfl(ib, q * 16 + col, 64);
        }
        const float* zr = z + (size_t)tok * 64 + quad * 16;
        float4v zv0 = *(const float4v*)(zr);
        float4v zv1 = *(const float4v*)(zr + 4);
        float4v zv2 = *(const float4v*)(zr + 8);
        float4v zv3 = *(const float4v*)(zr + 12);
        double ps[8];
        #pragma unroll
        for (int s = 0; s < 8; ++s) {
            int cc = (cand[s] < K) ? cand[s] : 0;
            const float* cr = cb + (size_t)cc * 64 + quad * 16;
            float4v c0 = *(const float4v*)(cr);
            float4v c1 = *(const float4v*)(cr + 4);
            float4v c2 = *(const float4v*)(cr + 8);
            float4v c3 = *(const float4v*)(cr + 12);
            double a = 0.0;
            #pragma unroll
            for (int j = 0; j < 4; ++j) {
                double e0 = (double)zv0[j] - (double)c0[j];
                double e1 = (double)zv1[j] - (double)c1[j];
                double e2 = (double)zv2[j] - (double)c2[j];
                double e3 = (double)zv3[j] - (double)c3[j];
                a = fma(e0, e0, a); a = fma(e1, e1, a);
                a = fma(e2, e2, a); a = fma(e3, e3, a);
            }
            ps[s] = (cand[s] < K) ? a : 1.0e300;
        }
        #pragma unroll
        for (int s = 0; s < 8; ++s) {
            ps[s] += __shfl_xor(ps[s], 16, 64);
            ps[s] += __shfl_xor(ps[s], 32, 64);
        }
        double bs = ps[0]; int bi = cand[0];
        #pragma unroll
        for (int s = 1; s < 8; ++s) {
            if (ps[s] < bs || (ps[s] == bs && cand[s] < bi)) { bs = ps[s]; bi = cand[s]; }
        }
        ibst[g] = bi;
    }

    const size_t off_idx = (size_t)NT * 64;

    if (lane < 32) {
        int tk = wtok0 + lane;
        if (tk < NT) {
            int ib = (lane < 16) ? ibst[0] : ibst[1];
            out[off_idx + tk] = (float)ib;
            if (smallK) atomicAdd(&hist[ib], 1);
            else        atomicAdd(&wsi[ib], 1);
        }
    }

    // Epilogue: quantized write + commitment loss (NO dw atomics — see header).
    float lsum = 0.f;
    #pragma unroll
    for (int i = 0; i < 8; ++i) {
        int tw  = i * 4 + quad;
        int g   = i >> 2;
        int idx = __shfl(ibst[g], tw & 15, 64);
        int token = wtok0 + tw;
        if (token < NT) {
            int d4 = col * 4;
            float4v zf = *(const float4v*)(z  + (size_t)token * 64 + d4);
            float4v qf = *(const float4v*)(cb + (size_t)idx   * 64 + d4);
            *(float4v*)(out + (size_t)token * 64 + d4) = qf;
            float e0 = zf[0] - qf[0], e1 = zf[1] - qf[1];
            float e2 = zf[2] - qf[2], e3 = zf[3] - qf[3];
            lsum += e0 * e0 + e1 * e1 + e2 * e2 + e3 * e3;
        }
    }
    #pragma unroll
    for (int off = 1; off < 64; off <<= 1) lsum += __shfl_xor(lsum, off, 64);
    if (lane == 0) atomicAdd(lossp, lsum);

    __syncthreads();
    if (smallK) {
        for (int k = tid; k < K; k += 512) {
            int c = hist[k];
            if (c) atomicAdd(&wsi[k], c);
        }
    }
}

// Owner-computes dw reduction: block b owns codes [b*cpb, b*cpb+cpb).
// Scan all token indices; ballot hits; 64-lane cooperative row-add into a
// private LDS accumulator (1 float/lane, LDS atomics only). Exclusive global
// writeout — zero global atomics.
__launch_bounds__(512)
__global__ void vq_dwred(const float* __restrict__ z,
                         const float* __restrict__ out_idx,
                         float* __restrict__ dwacc, int NT, int K, int cpb) {
    extern __shared__ float acc[];               // cpb*64 floats
    const int tid  = threadIdx.x;
    const int lane = tid & 63;
    const int wave = tid >> 6;
    const int k0   = blockIdx.x * cpb;
    const int kend = (k0 + cpb < K) ? (k0 + cpb) : K;
    const int nsl  = kend - k0;
    if (nsl <= 0) return;

    for (int i = tid; i < nsl * 64; i += 512) acc[i] = 0.f;
    __syncthreads();

    const int per_wave = (NT + 7) >> 3;          // 8 waves
    const int t0 = wave * per_wave;
    const int t1 = (t0 + per_wave < NT) ? (t0 + per_wave) : NT;
    for (int t = t0; t < t1; t += 64) {
        int token = t + lane;
        int idx = -1;
        if (token < t1) idx = (int)out_idx[token];
        bool hit = (idx >= k0) && (idx < kend);
        unsigned long long m = __ballot(hit);
        while (m) {
            int j = __ffsll((long long)m) - 1;
            m &= m - 1;
            int slot = __shfl(idx, j, 64) - k0;
            int tok  = t + j;
            atomicAdd(&acc[slot * 64 + lane], z[(size_t)tok * 64 + lane]);
        }
    }
    __syncthreads();
    for (int i = tid; i < nsl * 64; i += 512)
        dwacc[(size_t)k0 * 64 + i] = OMD * acc[i];
}

// Single block: n = sum(DECAY*cs + OMD*cnt), loss normalize.
__global__ void vq_nsum(const float* __restrict__ cs,
                        float* __restrict__ wsf, const int* __restrict__ wsi,
                        float* __restrict__ out, int NT, int K) {
    __shared__ float red[16];
    const int tid = threadIdx.x;
    const int KD = K * 64;
    float part = 0.f;
    for (int k = tid; k < K; k += 1024)
        part += DECAY * cs[k] + OMD * (float)wsi[k];
    #pragma unroll
    for (int off = 1; off < 64; off <<= 1) part += __shfl_xor(part, off, 64);
    if ((tid & 63) == 0) red[tid >> 6] = part;
    __syncthreads();
    if (tid == 0) {
        float nn = 0.f;
        #pragma unroll
        for (int i = 0; i < 16; ++i) nn += red[i];
        wsf[2 * K + KD + 1] = nn;                                 // n
        out[(size_t)NT * 64 + NT] = wsf[2 * K + KD] / ((float)NT * 64.0f);
    }
}

// Final: combine accumulators -> new_ema_w, new_codebook, new_cluster_size.
__global__ void vq_final(const float* __restrict__ cs,
                         const float* __restrict__ ema,
                         const float* __restrict__ wsf,
                         const int* __restrict__ wsi,
                         float* __restrict__ out, int NT, int K) {
    const int KD = K * 64;
    int t = blockIdx.x * 256 + threadIdx.x;
    if (t >= KD) return;
    const int k = t >> 6;
    const float n = wsf[2 * K + KD + 1];
    const float dw = DECAY * ema[t] + wsf[K + t];
    const float ncs = DECAY * cs[k] + OMD * (float)wsi[k];
    const float csn = (ncs + EPSV) / (n + (float)K * EPSV) * n;
    const size_t off_cb  = (size_t)NT * 64 + NT + 1;
    const size_t off_cs  = off_cb + (size_t)KD;
    const size_t off_ema = off_cs + K;
    out[off_cb  + t] = dw / csn;
    out[off_ema + t] = dw;
    if ((t & 63) == 0) out[off_cs + k] = ncs;
}

extern "C" void kernel_launch(void* const* d_in, const int* in_sizes, int n_in,
                              void* d_out, int out_size, void* d_ws, size_t ws_size,
                              hipStream_t stream) {
    const float* z   = (const float*)d_in[0];
    const float* cb  = (const float*)d_in[1];
    const float* cs  = (const float*)d_in[2];
    const float* ema = (const float*)d_in[3];
    float* out = (float*)d_out;
    float* wsf = (float*)d_ws;
    int*   wsi = (int*)d_ws;

    const int NT = in_sizes[0] / 64;
    const int K  = in_sizes[2];
    const int KD = K * 64;

    const int cpb  = (K + 255) / 256;            // codes per reducer block
    const int nblk = (K + cpb - 1) / cpb;
    const size_t dwlds = (size_t)cpb * 64 * sizeof(float);

    vq_prep<<<(KD + 255) / 256, 256, 0, stream>>>(cb, wsf, wsi, K, NT);
    vq_main<<<(NT + 255) / 256, 512, 0, stream>>>(z, cb, wsf, wsi, out, NT, K);
    vq_dwred<<<nblk, 512, dwlds, stream>>>(z, out + (size_t)NT * 64,
                                           wsf + K, NT, K, cpb);
    vq_nsum<<<1, 1024, 0, stream>>>(cs, wsf, wsi, out, NT, K);
    vq_final<<<(KD + 255) / 256, 256, 0, stream>>>(cs, ema, wsf, wsi, out, NT, K);
}

// Round 3
// 427.458 us; speedup vs baseline: 1.2664x; 1.0071x over previous
//
#include <hip/hip_runtime.h>
#include <hip/hip_bf16.h>

// VectorQuantizer on MI355X — R10:
//  (a) cooperative coalesced fp64 refine in vq_main (unchanged from R9).
//  (b) dw owner-computes reduction, restructured for latency hiding:
//      token-split x S (default 8) with exclusive per-split global partials
//      (zero global atomics), 2048 small blocks (8/CU), float4 idx scan
//      (256 tokens/wave-iter), and 4-token batched z-row gathers (the 4
//      lane-quads each fetch a different hit row in one instruction).
//      R9's version (256 blocks, serial per-hit gathers) was 250 us at 8.8%
//      occupancy — latency-starved, not bandwidth- or atomic-bound.
// Inputs (fp32): z[NT,64], codebook[K,64], cluster_size[K], ema_w[K,64]
// d_out (fp32): quantized[NT*64] | indices[NT] | loss[1] | new_codebook[K*64] |
//   new_cluster_size[K] | new_ema_w[K*64]
// ws dwords: cnt[K](int) | cnormp[K] | loss | n | partial[S][K*64]

#define DECAY 0.99f
#define OMD   0.01f
#define EPSV  1e-5f
#define BIASF 192.0f    // folded into MFMA acc init: score' = 192 + z.c - |c|^2/2 > 0

typedef __attribute__((ext_vector_type(8))) __bf16 bf16x8;
typedef __attribute__((ext_vector_type(4))) float  float4v;

static __device__ __forceinline__ unsigned short bfbits(float f) {
    __bf16 h = (__bf16)f;
    return __builtin_bit_cast(unsigned short, h);
}
static __device__ __forceinline__ bf16x8 cvt8(float4v a, float4v b) {
    bf16x8 r;
    r[0] = (__bf16)a[0]; r[1] = (__bf16)a[1]; r[2] = (__bf16)a[2]; r[3] = (__bf16)a[3];
    r[4] = (__bf16)b[0]; r[5] = (__bf16)b[1]; r[6] = (__bf16)b[2]; r[7] = (__bf16)b[3];
    return r;
}

// key low 8 bits = per-lane candidate number iter = (c<<6)|(t<<2)|r
static __device__ __forceinline__ int dec_idx(unsigned key, int quad) {
    int iter = key & 255;
    return ((iter >> 6) << 8) + (((iter >> 2) & 15) << 4) + (quad << 2) + (iter & 3);
}

__global__ void vq_prep(const float* __restrict__ cb,
                        float* __restrict__ wsf, int* __restrict__ wsi,
                        int K, int NT, int S) {
    const int KD = K * 64;
    int t = blockIdx.x * 256 + threadIdx.x;
    if (t < S * KD) wsf[2 * K + 2 + t] = 0.f;     // partial zero-init
    if (t < K) {
        wsi[t] = 0;                               // cnt
        const float4v* cp = (const float4v*)(cb + (size_t)t * 64);
        float s = 0.f;
        #pragma unroll
        for (int i = 0; i < 16; ++i) {
            float4v v = cp[i];
            s += v[0] * v[0] + v[1] * v[1] + v[2] * v[2] + v[3] * v[3];
        }
        wsf[K + t] = BIASF - 0.5f * s;            // cnormp
    }
    if (t == 0) wsf[2 * K] = 0.f;                 // loss
}

// 512 threads = 8 waves; 256 tokens/block (32/wave); codebook bf16 in LDS.
__launch_bounds__(512)
__global__ void vq_main(const float* __restrict__ z,
                        const float* __restrict__ cb,
                        float* __restrict__ wsf, int* __restrict__ wsi,
                        float* __restrict__ out,
                        int NT, int K) {
    __shared__ __align__(16) unsigned short cbs[256 * 72];   // 36 KB
    __shared__ float cns[256];
    __shared__ int hist[1024];

    const int tid  = threadIdx.x;
    const int lane = tid & 63;
    const int wave = tid >> 6;
    const int col  = lane & 15;
    const int quad = lane >> 4;
    const int wtok0 = blockIdx.x * 256 + wave * 32;
    const float* cnormp = wsf + K;
    float* lossp = wsf + 2 * K;
    const bool smallK = (K <= 1024);

    for (int i = tid; i < 1024; i += 512) hist[i] = 0;

    bf16x8 bf0[2], bf1[2];
    #pragma unroll
    for (int g = 0; g < 2; ++g) {
        int tok = wtok0 + g * 16 + col;
        if (tok >= NT) tok = NT - 1;
        const float* zp = z + (size_t)tok * 64 + quad * 8;
        float4v f0 = *(const float4v*)(zp);
        float4v f1 = *(const float4v*)(zp + 4);
        float4v f2 = *(const float4v*)(zp + 32);
        float4v f3 = *(const float4v*)(zp + 36);
        bf0[g] = cvt8(f0, f1);
        bf1[g] = cvt8(f2, f3);
    }

    unsigned k1[2] = { 0u, 0u }, k2[2] = { 0u, 0u };
    const unsigned kmask = 0xFFFFFF00u;
    const int nchunk = (K + 255) >> 8;

    for (int c = 0; c < nchunk; ++c) {
        #pragma unroll
        for (int i = 0; i < 8; ++i) {
            int f4 = (i * 512 + tid) * 4;
            int row = f4 >> 6, d = f4 & 63;
            int code = c * 256 + row;
            uint2 p;
            if (code < K) {
                float4v v = *(const float4v*)(cb + (size_t)code * 64 + d);
                p.x = (unsigned int)bfbits(v[0]) | ((unsigned int)bfbits(v[1]) << 16);
                p.y = (unsigned int)bfbits(v[2]) | ((unsigned int)bfbits(v[3]) << 16);
            } else { p.x = 0u; p.y = 0u; }
            *(uint2*)(&cbs[row * 72 + d]) = p;
        }
        if (tid < 256) {
            int code = c * 256 + tid;
            cns[tid] = (code < K) ? cnormp[code] : 0.0f;
        }
        __syncthreads();

        #pragma unroll 4
        for (int t = 0; t < 16; ++t) {
            const unsigned short* arow = cbs + (t * 16 + col) * 72;
            bf16x8 a0 = *(const bf16x8*)(arow + quad * 8);
            bf16x8 a1 = *(const bf16x8*)(arow + 32 + quad * 8);
            float4v cni = *(const float4v*)(cns + t * 16 + quad * 4);
            const int iterbase = (c << 6) | (t << 2);
            #pragma unroll
            for (int g = 0; g < 2; ++g) {
                float4v acc = cni;              // = BIAS - |c|^2/2
                acc = __builtin_amdgcn_mfma_f32_16x16x32_bf16(a0, bf0[g], acc, 0, 0, 0);
                acc = __builtin_amdgcn_mfma_f32_16x16x32_bf16(a1, bf1[g], acc, 0, 0, 0);
                #pragma unroll
                for (int r = 0; r < 4; ++r) {
                    unsigned kb = (__float_as_uint(acc[r]) & kmask) | (unsigned)(iterbase + r);
                    unsigned lo = k2[g] > kb ? k2[g] : kb;
                    k2[g] = k1[g] < lo ? k1[g] : lo;
                    k1[g] = k1[g] > kb ? k1[g] : kb;
                }
            }
        }
        __syncthreads();
    }

    // Cooperative exact refine (R9): 4 quad-lanes per token jointly rerank the
    // token's 8 candidates in fp64; each lane covers a 16-dim slice.
    int ibst[2];
    #pragma unroll
    for (int g = 0; g < 2; ++g) {
        int tok = wtok0 + g * 16 + col;
        if (tok >= NT) tok = NT - 1;
        int ia = dec_idx(k1[g], quad);
        int ib = dec_idx(k2[g], quad);
        int cand[8];
        #pragma unroll
        for (int q = 0; q < 4; ++q) {
            cand[2 * q]     = __shfl(ia, q * 16 + col, 64);
            cand[2 * q + 1] = __shfl(ib, q * 16 + col, 64);
        }
        const float* zr = z + (size_t)tok * 64 + quad * 16;
        float4v zv0 = *(const float4v*)(zr);
        float4v zv1 = *(const float4v*)(zr + 4);
        float4v zv2 = *(const float4v*)(zr + 8);
        float4v zv3 = *(const float4v*)(zr + 12);
        double ps[8];
        #pragma unroll
        for (int s = 0; s < 8; ++s) {
            int cc = (cand[s] < K) ? cand[s] : 0;
            const float* cr = cb + (size_t)cc * 64 + quad * 16;
            float4v c0 = *(const float4v*)(cr);
            float4v c1 = *(const float4v*)(cr + 4);
            float4v c2 = *(const float4v*)(cr + 8);
            float4v c3 = *(const float4v*)(cr + 12);
            double a = 0.0;
            #pragma unroll
            for (int j = 0; j < 4; ++j) {
                double e0 = (double)zv0[j] - (double)c0[j];
                double e1 = (double)zv1[j] - (double)c1[j];
                double e2 = (double)zv2[j] - (double)c2[j];
                double e3 = (double)zv3[j] - (double)c3[j];
                a = fma(e0, e0, a); a = fma(e1, e1, a);
                a = fma(e2, e2, a); a = fma(e3, e3, a);
            }
            ps[s] = (cand[s] < K) ? a : 1.0e300;
        }
        #pragma unroll
        for (int s = 0; s < 8; ++s) {
            ps[s] += __shfl_xor(ps[s], 16, 64);
            ps[s] += __shfl_xor(ps[s], 32, 64);
        }
        double bs = ps[0]; int bi = cand[0];
        #pragma unroll
        for (int s = 1; s < 8; ++s) {
            if (ps[s] < bs || (ps[s] == bs && cand[s] < bi)) { bs = ps[s]; bi = cand[s]; }
        }
        ibst[g] = bi;
    }

    const size_t off_idx = (size_t)NT * 64;

    if (lane < 32) {
        int tk = wtok0 + lane;
        if (tk < NT) {
            int ib = (lane < 16) ? ibst[0] : ibst[1];
            out[off_idx + tk] = (float)ib;
            if (smallK) atomicAdd(&hist[ib], 1);
            else        atomicAdd(&wsi[ib], 1);
        }
    }

    // Epilogue: quantized write + commitment loss.
    float lsum = 0.f;
    #pragma unroll
    for (int i = 0; i < 8; ++i) {
        int tw  = i * 4 + quad;
        int g   = i >> 2;
        int idx = __shfl(ibst[g], tw & 15, 64);
        int token = wtok0 + tw;
        if (token < NT) {
            int d4 = col * 4;
            float4v zf = *(const float4v*)(z  + (size_t)token * 64 + d4);
            float4v qf = *(const float4v*)(cb + (size_t)idx   * 64 + d4);
            *(float4v*)(out + (size_t)token * 64 + d4) = qf;
            float e0 = zf[0] - qf[0], e1 = zf[1] - qf[1];
            float e2 = zf[2] - qf[2], e3 = zf[3] - qf[3];
            lsum += e0 * e0 + e1 * e1 + e2 * e2 + e3 * e3;
        }
    }
    #pragma unroll
    for (int off = 1; off < 64; off <<= 1) lsum += __shfl_xor(lsum, off, 64);
    if (lane == 0) atomicAdd(lossp, lsum);

    __syncthreads();
    if (smallK) {
        for (int k = tid; k < K; k += 512) {
            int c = hist[k];
            if (c) atomicAdd(&wsi[k], c);
        }
    }
}

// Owner-computes dw reduction, split edition.
// blockIdx = split * nblkK + cblk. Block owns codes [cblk*cpb, +cpb) within
// token range [split*tpers, +tpers). float4 idx scan (256 tokens/wave-iter);
// hits processed 4 at a time: lane-quad g fetches hit-row g via one float4
// load (4 rows per memory instruction), predicated LDS atomics accumulate.
// Exclusive writeout into partial[split] — zero global atomics.
__launch_bounds__(256)
__global__ void vq_dwred(const float* __restrict__ z,
                         const float* __restrict__ out_idx,
                         float* __restrict__ partial,
                         int NT, int K, int cpb, int nblkK) {
    extern __shared__ float acc[];               // cpb*64 floats
    const int cblk  = blockIdx.x % nblkK;
    const int split = blockIdx.x / nblkK;
    const int S     = gridDim.x / nblkK;
    const int k0    = cblk * cpb;
    const int kend  = (k0 + cpb < K) ? (k0 + cpb) : K;
    const int nsl   = kend - k0;
    if (nsl <= 0) return;

    const int tid  = threadIdx.x;
    const int lane = tid & 63;
    const int wave = tid >> 6;                   // 4 waves
    const int grp  = lane >> 4;
    const int sub  = lane & 15;

    for (int i = tid; i < nsl * 64; i += 256) acc[i] = 0.f;
    __syncthreads();

    const int tpers = (NT + S - 1) / S;
    const int T0 = split * tpers;
    const int T1 = (T0 + tpers < NT) ? (T0 + tpers) : NT;

    for (int t = T0 + wave * 256; t < T1; t += 1024) {
        int id[4];
        if (t + 256 <= T1) {
            float4v iv = *(const float4v*)(out_idx + t + lane * 4);
            id[0] = (int)iv[0]; id[1] = (int)iv[1];
            id[2] = (int)iv[2]; id[3] = (int)iv[3];
        } else {
            #pragma unroll
            for (int c = 0; c < 4; ++c) {
                int token = t + lane * 4 + c;
                id[c] = (token < T1) ? (int)out_idx[token] : -1;
            }
        }
        #pragma unroll
        for (int c = 0; c < 4; ++c) {
            bool hit = (id[c] >= k0) && (id[c] < kend);
            unsigned long long m = __ballot(hit);
            while (m) {
                int js[4]; int cnt = 0;
                #pragma unroll
                for (int u = 0; u < 4; ++u) {
                    if (m) { js[u] = __ffsll((long long)m) - 1; m &= m - 1; ++cnt; }
                    else   { js[u] = js[0]; }
                }
                int jg   = js[grp];
                int slot = __shfl(id[c], jg, 64) - k0;
                int tok  = t + jg * 4 + c;
                float4v zv = *(const float4v*)(z + (size_t)tok * 64 + sub * 4);
                if (grp < cnt) {
                    float* ap = acc + slot * 64 + sub * 4;
                    atomicAdd(ap + 0, zv[0]);
                    atomicAdd(ap + 1, zv[1]);
                    atomicAdd(ap + 2, zv[2]);
                    atomicAdd(ap + 3, zv[3]);
                }
            }
        }
    }
    __syncthreads();
    const size_t KD = (size_t)K * 64;
    for (int i = tid; i < nsl * 64; i += 256)
        partial[(size_t)split * KD + (size_t)k0 * 64 + i] = acc[i];
}

// Single block: n = sum(DECAY*cs + OMD*cnt), loss normalize.
__global__ void vq_nsum(const float* __restrict__ cs,
                        float* __restrict__ wsf, const int* __restrict__ wsi,
                        float* __restrict__ out, int NT, int K) {
    __shared__ float red[16];
    const int tid = threadIdx.x;
    float part = 0.f;
    for (int k = tid; k < K; k += 1024)
        part += DECAY * cs[k] + OMD * (float)wsi[k];
    #pragma unroll
    for (int off = 1; off < 64; off <<= 1) part += __shfl_xor(part, off, 64);
    if ((tid & 63) == 0) red[tid >> 6] = part;
    __syncthreads();
    if (tid == 0) {
        float nn = 0.f;
        #pragma unroll
        for (int i = 0; i < 16; ++i) nn += red[i];
        wsf[2 * K + 1] = nn;                                      // n
        out[(size_t)NT * 64 + NT] = wsf[2 * K] / ((float)NT * 64.0f);
    }
}

// Final: sum split partials -> new_ema_w, new_codebook, new_cluster_size.
__global__ void vq_final(const float* __restrict__ cs,
                         const float* __restrict__ ema,
                         const float* __restrict__ wsf,
                         const int* __restrict__ wsi,
                         float* __restrict__ out, int NT, int K, int S) {
    const int KD = K * 64;
    int t = blockIdx.x * 256 + threadIdx.x;
    if (t >= KD) return;
    const int k = t >> 6;
    const float n = wsf[2 * K + 1];
    float dsum = 0.f;
    for (int s = 0; s < S; ++s) dsum += wsf[2 * K + 2 + (size_t)s * KD + t];
    const float dw = DECAY * ema[t] + OMD * dsum;
    const float ncs = DECAY * cs[k] + OMD * (float)wsi[k];
    const float csn = (ncs + EPSV) / (n + (float)K * EPSV) * n;
    const size_t off_cb  = (size_t)NT * 64 + NT + 1;
    const size_t off_cs  = off_cb + (size_t)KD;
    const size_t off_ema = off_cs + K;
    out[off_cb  + t] = dw / csn;
    out[off_ema + t] = dw;
    if ((t & 63) == 0) out[off_cs + k] = ncs;
}

extern "C" void kernel_launch(void* const* d_in, const int* in_sizes, int n_in,
                              void* d_out, int out_size, void* d_ws, size_t ws_size,
                              hipStream_t stream) {
    const float* z   = (const float*)d_in[0];
    const float* cb  = (const float*)d_in[1];
    const float* cs  = (const float*)d_in[2];
    const float* ema = (const float*)d_in[3];
    float* out = (float*)d_out;
    float* wsf = (float*)d_ws;
    int*   wsi = (int*)d_ws;

    const int NT = in_sizes[0] / 64;
    const int K  = in_sizes[2];
    const int KD = K * 64;

    int cpb = (K + 255) / 256; if (cpb < 1) cpb = 1;
    const int nblkK = (K + cpb - 1) / cpb;

    // Shrink split count if workspace can't hold the partials.
    size_t avail = ws_size / 4;                  // dwords
    int S = 8;
    while (S > 1 && (size_t)2 * K + 2 + (size_t)S * KD > avail) S >>= 1;

    vq_prep<<<(S * KD + 255) / 256, 256, 0, stream>>>(cb, wsf, wsi, K, NT, S);
    vq_main<<<(NT + 255) / 256, 512, 0, stream>>>(z, cb, wsf, wsi, out, NT, K);
    vq_dwred<<<S * nblkK, 256, (size_t)cpb * 64 * sizeof(float), stream>>>(
        z, out + (size_t)NT * 64, wsf + 2 * K + 2, NT, K, cpb, nblkK);
    vq_nsum<<<1, 1024, 0, stream>>>(cs, wsf, wsi, out, NT, K);
    vq_final<<<(KD + 255) / 256, 256, 0, stream>>>(cs, ema, wsf, wsi, out, NT, K, S);
}

// Round 4
// 382.397 us; speedup vs baseline: 1.4156x; 1.1178x over previous
//
#include <hip/hip_runtime.h>
#include <hip/hip_bf16.h>

// VectorQuantizer on MI355X — R11:
//  (a) cooperative coalesced fp64 refine in vq_main (unchanged since R9).
//  (b) dw: token-owner blocks. S=64 blocks x 1024 thr; each owns NT/S tokens
//      and accumulates the FULL K x 64 dw in LDS over ceil(K/256) passes of
//      256 codes (64KB LDS). Exclusive per-block global partials (no global
//      atomics, no pre-zero); vq_final sums the S copies.
//      Kills the owner-computes scan redundancy (R9/R10: 256 blocks re-read
//      ALL idx -> 33.5M checks, 240-250us at 14% occupancy; here idx is read
//      npass x NT = 4x total, z exactly once).
//  (c) vq_nsum folded into dwred block 0 (cnt ready by kernel order).
// Inputs (fp32): z[NT,64], codebook[K,64], cluster_size[K], ema_w[K,64]
// d_out (fp32): quantized[NT*64] | indices[NT] | loss[1] | new_codebook[K*64] |
//   new_cluster_size[K] | new_ema_w[K*64]
// ws dwords: cnt[K](int) | cnormp[K] | loss | n | partial[S][K*64]

#define DECAY 0.99f
#define OMD   0.01f
#define EPSV  1e-5f
#define BIASF 192.0f    // folded into MFMA acc init: score' = 192 + z.c - |c|^2/2 > 0
#define KHALF 256       // codes per dw pass (LDS = KHALF*64*4 = 64KB)

typedef __attribute__((ext_vector_type(8))) __bf16 bf16x8;
typedef __attribute__((ext_vector_type(4))) float  float4v;

static __device__ __forceinline__ unsigned short bfbits(float f) {
    __bf16 h = (__bf16)f;
    return __builtin_bit_cast(unsigned short, h);
}
static __device__ __forceinline__ bf16x8 cvt8(float4v a, float4v b) {
    bf16x8 r;
    r[0] = (__bf16)a[0]; r[1] = (__bf16)a[1]; r[2] = (__bf16)a[2]; r[3] = (__bf16)a[3];
    r[4] = (__bf16)b[0]; r[5] = (__bf16)b[1]; r[6] = (__bf16)b[2]; r[7] = (__bf16)b[3];
    return r;
}

// key low 8 bits = per-lane candidate number iter = (c<<6)|(t<<2)|r
static __device__ __forceinline__ int dec_idx(unsigned key, int quad) {
    int iter = key & 255;
    return ((iter >> 6) << 8) + (((iter >> 2) & 15) << 4) + (quad << 2) + (iter & 3);
}

__global__ void vq_prep(const float* __restrict__ cb,
                        float* __restrict__ wsf, int* __restrict__ wsi,
                        int K, int NT) {
    int t = blockIdx.x * 256 + threadIdx.x;
    if (t < K) {
        wsi[t] = 0;                               // cnt
        const float4v* cp = (const float4v*)(cb + (size_t)t * 64);
        float s = 0.f;
        #pragma unroll
        for (int i = 0; i < 16; ++i) {
            float4v v = cp[i];
            s += v[0] * v[0] + v[1] * v[1] + v[2] * v[2] + v[3] * v[3];
        }
        wsf[K + t] = BIASF - 0.5f * s;            // cnormp
    }
    if (t == 0) wsf[2 * K] = 0.f;                 // loss
}

// 512 threads = 8 waves; 256 tokens/block (32/wave); codebook bf16 in LDS.
__launch_bounds__(512)
__global__ void vq_main(const float* __restrict__ z,
                        const float* __restrict__ cb,
                        float* __restrict__ wsf, int* __restrict__ wsi,
                        float* __restrict__ out,
                        int NT, int K) {
    __shared__ __align__(16) unsigned short cbs[256 * 72];   // 36 KB
    __shared__ float cns[256];
    __shared__ int hist[1024];

    const int tid  = threadIdx.x;
    const int lane = tid & 63;
    const int wave = tid >> 6;
    const int col  = lane & 15;
    const int quad = lane >> 4;
    const int wtok0 = blockIdx.x * 256 + wave * 32;
    const float* cnormp = wsf + K;
    float* lossp = wsf + 2 * K;
    const bool smallK = (K <= 1024);

    for (int i = tid; i < 1024; i += 512) hist[i] = 0;

    bf16x8 bf0[2], bf1[2];
    #pragma unroll
    for (int g = 0; g < 2; ++g) {
        int tok = wtok0 + g * 16 + col;
        if (tok >= NT) tok = NT - 1;
        const float* zp = z + (size_t)tok * 64 + quad * 8;
        float4v f0 = *(const float4v*)(zp);
        float4v f1 = *(const float4v*)(zp + 4);
        float4v f2 = *(const float4v*)(zp + 32);
        float4v f3 = *(const float4v*)(zp + 36);
        bf0[g] = cvt8(f0, f1);
        bf1[g] = cvt8(f2, f3);
    }

    unsigned k1[2] = { 0u, 0u }, k2[2] = { 0u, 0u };
    const unsigned kmask = 0xFFFFFF00u;
    const int nchunk = (K + 255) >> 8;

    for (int c = 0; c < nchunk; ++c) {
        #pragma unroll
        for (int i = 0; i < 8; ++i) {
            int f4 = (i * 512 + tid) * 4;
            int row = f4 >> 6, d = f4 & 63;
            int code = c * 256 + row;
            uint2 p;
            if (code < K) {
                float4v v = *(const float4v*)(cb + (size_t)code * 64 + d);
                p.x = (unsigned int)bfbits(v[0]) | ((unsigned int)bfbits(v[1]) << 16);
                p.y = (unsigned int)bfbits(v[2]) | ((unsigned int)bfbits(v[3]) << 16);
            } else { p.x = 0u; p.y = 0u; }
            *(uint2*)(&cbs[row * 72 + d]) = p;
        }
        if (tid < 256) {
            int code = c * 256 + tid;
            cns[tid] = (code < K) ? cnormp[code] : 0.0f;
        }
        __syncthreads();

        #pragma unroll 4
        for (int t = 0; t < 16; ++t) {
            const unsigned short* arow = cbs + (t * 16 + col) * 72;
            bf16x8 a0 = *(const bf16x8*)(arow + quad * 8);
            bf16x8 a1 = *(const bf16x8*)(arow + 32 + quad * 8);
            float4v cni = *(const float4v*)(cns + t * 16 + quad * 4);
            const int iterbase = (c << 6) | (t << 2);
            #pragma unroll
            for (int g = 0; g < 2; ++g) {
                float4v acc = cni;              // = BIAS - |c|^2/2
                acc = __builtin_amdgcn_mfma_f32_16x16x32_bf16(a0, bf0[g], acc, 0, 0, 0);
                acc = __builtin_amdgcn_mfma_f32_16x16x32_bf16(a1, bf1[g], acc, 0, 0, 0);
                #pragma unroll
                for (int r = 0; r < 4; ++r) {
                    unsigned kb = (__float_as_uint(acc[r]) & kmask) | (unsigned)(iterbase + r);
                    unsigned lo = k2[g] > kb ? k2[g] : kb;
                    k2[g] = k1[g] < lo ? k1[g] : lo;
                    k1[g] = k1[g] > kb ? k1[g] : kb;
                }
            }
        }
        __syncthreads();
    }

    // Cooperative exact refine (R9): 4 quad-lanes per token jointly rerank the
    // token's 8 candidates in fp64; each lane covers a 16-dim slice.
    int ibst[2];
    #pragma unroll
    for (int g = 0; g < 2; ++g) {
        int tok = wtok0 + g * 16 + col;
        if (tok >= NT) tok = NT - 1;
        int ia = dec_idx(k1[g], quad);
        int ib = dec_idx(k2[g], quad);
        int cand[8];
        #pragma unroll
        for (int q = 0; q < 4; ++q) {
            cand[2 * q]     = __shfl(ia, q * 16 + col, 64);
            cand[2 * q + 1] = __shfl(ib, q * 16 + col, 64);
        }
        const float* zr = z + (size_t)tok * 64 + quad * 16;
        float4v zv0 = *(const float4v*)(zr);
        float4v zv1 = *(const float4v*)(zr + 4);
        float4v zv2 = *(const float4v*)(zr + 8);
        float4v zv3 = *(const float4v*)(zr + 12);
        double ps[8];
        #pragma unroll
        for (int s = 0; s < 8; ++s) {
            int cc = (cand[s] < K) ? cand[s] : 0;
            const float* cr = cb + (size_t)cc * 64 + quad * 16;
            float4v c0 = *(const float4v*)(cr);
            float4v c1 = *(const float4v*)(cr + 4);
            float4v c2 = *(const float4v*)(cr + 8);
            float4v c3 = *(const float4v*)(cr + 12);
            double a = 0.0;
            #pragma unroll
            for (int j = 0; j < 4; ++j) {
                double e0 = (double)zv0[j] - (double)c0[j];
                double e1 = (double)zv1[j] - (double)c1[j];
                double e2 = (double)zv2[j] - (double)c2[j];
                double e3 = (double)zv3[j] - (double)c3[j];
                a = fma(e0, e0, a); a = fma(e1, e1, a);
                a = fma(e2, e2, a); a = fma(e3, e3, a);
            }
            ps[s] = (cand[s] < K) ? a : 1.0e300;
        }
        #pragma unroll
        for (int s = 0; s < 8; ++s) {
            ps[s] += __shfl_xor(ps[s], 16, 64);
            ps[s] += __shfl_xor(ps[s], 32, 64);
        }
        double bs = ps[0]; int bi = cand[0];
        #pragma unroll
        for (int s = 1; s < 8; ++s) {
            if (ps[s] < bs || (ps[s] == bs && cand[s] < bi)) { bs = ps[s]; bi = cand[s]; }
        }
        ibst[g] = bi;
    }

    const size_t off_idx = (size_t)NT * 64;

    if (lane < 32) {
        int tk = wtok0 + lane;
        if (tk < NT) {
            int ib = (lane < 16) ? ibst[0] : ibst[1];
            out[off_idx + tk] = (float)ib;
            if (smallK) atomicAdd(&hist[ib], 1);
            else        atomicAdd(&wsi[ib], 1);
        }
    }

    // Epilogue: quantized write + commitment loss.
    float lsum = 0.f;
    #pragma unroll
    for (int i = 0; i < 8; ++i) {
        int tw  = i * 4 + quad;
        int g   = i >> 2;
        int idx = __shfl(ibst[g], tw & 15, 64);
        int token = wtok0 + tw;
        if (token < NT) {
            int d4 = col * 4;
            float4v zf = *(const float4v*)(z  + (size_t)token * 64 + d4);
            float4v qf = *(const float4v*)(cb + (size_t)idx   * 64 + d4);
            *(float4v*)(out + (size_t)token * 64 + d4) = qf;
            float e0 = zf[0] - qf[0], e1 = zf[1] - qf[1];
            float e2 = zf[2] - qf[2], e3 = zf[3] - qf[3];
            lsum += e0 * e0 + e1 * e1 + e2 * e2 + e3 * e3;
        }
    }
    #pragma unroll
    for (int off = 1; off < 64; off <<= 1) lsum += __shfl_xor(lsum, off, 64);
    if (lane == 0) atomicAdd(lossp, lsum);

    __syncthreads();
    if (smallK) {
        for (int k = tid; k < K; k += 512) {
            int c = hist[k];
            if (c) atomicAdd(&wsi[k], c);
        }
    }
}

// Token-owner dw reduction. Block b owns tokens [b*C, b*C+C). For each pass
// (256 codes), zero 64KB LDS acc, scan own idx (coalesced; ~npass re-reads),
// quad-batched z-row gathers (4 rows / memory instruction) into LDS atomics,
// then exclusive writeout to partial[b]. Block 0 additionally computes
// n = sum(DECAY*cs + OMD*cnt) and normalizes the loss output.
__launch_bounds__(1024)
__global__ void vq_dwred(const float* __restrict__ z,
                         const float* __restrict__ out_idx,
                         const float* __restrict__ cs,
                         float* __restrict__ wsf, const int* __restrict__ wsi,
                         float* __restrict__ partial,
                         float* __restrict__ out,
                         int NT, int K) {
    extern __shared__ float acc[];               // KHALF*64 floats = 64KB
    __shared__ float red[16];

    const int tid  = threadIdx.x;
    const int lane = tid & 63;
    const int wave = tid >> 6;                   // 16 waves
    const int grp  = lane >> 4;
    const int sub  = lane & 15;
    const int S    = gridDim.x;
    const size_t KD = (size_t)K * 64;

    if (blockIdx.x == 0) {
        // folded nsum duty (cnt ready: vq_main completed before this kernel)
        float part = 0.f;
        for (int k = tid; k < K; k += 1024)
            part += DECAY * cs[k] + OMD * (float)wsi[k];
        #pragma unroll
        for (int off = 1; off < 64; off <<= 1) part += __shfl_xor(part, off, 64);
        if (lane == 0) red[wave] = part;
        __syncthreads();
        if (tid == 0) {
            float nn = 0.f;
            #pragma unroll
            for (int i = 0; i < 16; ++i) nn += red[i];
            wsf[2 * K + 1] = nn;                                  // n
            out[(size_t)NT * 64 + NT] = wsf[2 * K] / ((float)NT * 64.0f);
        }
    }

    const int C  = (NT + S - 1) / S;
    const int T0 = blockIdx.x * C;
    const int T1 = (T0 + C < NT) ? (T0 + C) : NT;
    const int npass = (K + KHALF - 1) / KHALF;

    for (int p = 0; p < npass; ++p) {
        const int k0   = p * KHALF;
        const int kend = (k0 + KHALF < K) ? (k0 + KHALF) : K;
        for (int i = tid; i < KHALF * 64; i += 1024) acc[i] = 0.f;
        __syncthreads();

        for (int t = T0 + wave * 64; t < T1; t += 1024) {
            int token = t + lane;
            int code = -1;
            if (token < T1) code = (int)out_idx[token];
            bool hit = (code >= k0) && (code < kend);
            unsigned long long m = __ballot(hit);
            while (m) {
                int js[4]; int cnt = 0;
                #pragma unroll
                for (int u = 0; u < 4; ++u) {
                    if (m) { js[u] = __ffsll((long long)m) - 1; m &= m - 1; ++cnt; }
                    else   { js[u] = js[0]; }
                }
                int jg   = js[grp];
                int slot = __shfl(code, jg, 64) - k0;
                int tok  = t + jg;
                float4v zv = *(const float4v*)(z + (size_t)tok * 64 + sub * 4);
                if (grp < cnt) {
                    float* ap = acc + slot * 64 + sub * 4;
                    atomicAdd(ap + 0, zv[0]);
                    atomicAdd(ap + 1, zv[1]);
                    atomicAdd(ap + 2, zv[2]);
                    atomicAdd(ap + 3, zv[3]);
                }
            }
        }
        __syncthreads();
        for (int i = tid; i < (kend - k0) * 64; i += 1024)
            partial[blockIdx.x * KD + (size_t)k0 * 64 + i] = acc[i];
        __syncthreads();
    }
}

// Final: sum S exclusive partials -> new_ema_w, new_codebook, new_cluster_size.
__global__ void vq_final(const float* __restrict__ cs,
                         const float* __restrict__ ema,
                         const float* __restrict__ wsf,
                         const int* __restrict__ wsi,
                         const float* __restrict__ partial,
                         float* __restrict__ out, int NT, int K, int S) {
    const int KD = K * 64;
    int t = blockIdx.x * 256 + threadIdx.x;
    if (t >= KD) return;
    const int k = t >> 6;
    const float n = wsf[2 * K + 1];
    float dsum = 0.f;
    for (int s = 0; s < S; ++s) dsum += partial[(size_t)s * KD + t];
    const float dw = DECAY * ema[t] + OMD * dsum;
    const float ncs = DECAY * cs[k] + OMD * (float)wsi[k];
    const float csn = (ncs + EPSV) / (n + (float)K * EPSV) * n;
    const size_t off_cb  = (size_t)NT * 64 + NT + 1;
    const size_t off_cs  = off_cb + (size_t)KD;
    const size_t off_ema = off_cs + K;
    out[off_cb  + t] = dw / csn;
    out[off_ema + t] = dw;
    if ((t & 63) == 0) out[off_cs + k] = ncs;
}

extern "C" void kernel_launch(void* const* d_in, const int* in_sizes, int n_in,
                              void* d_out, int out_size, void* d_ws, size_t ws_size,
                              hipStream_t stream) {
    const float* z   = (const float*)d_in[0];
    const float* cb  = (const float*)d_in[1];
    const float* cs  = (const float*)d_in[2];
    const float* ema = (const float*)d_in[3];
    float* out = (float*)d_out;
    float* wsf = (float*)d_ws;
    int*   wsi = (int*)d_ws;

    const int NT = in_sizes[0] / 64;
    const int K  = in_sizes[2];
    const int KD = K * 64;

    // Shrink partial-copy count if workspace can't hold S*KD + header.
    size_t avail = ws_size / 4;                  // dwords
    int S = 64;
    while (S > 1 && (size_t)2 * K + 2 + (size_t)S * KD > avail) S >>= 1;

    float* partial = wsf + 2 * K + 2;

    vq_prep<<<(K + 255) / 256, 256, 0, stream>>>(cb, wsf, wsi, K, NT);
    vq_main<<<(NT + 255) / 256, 512, 0, stream>>>(z, cb, wsf, wsi, out, NT, K);
    vq_dwred<<<S, 1024, (size_t)KHALF * 64 * sizeof(float), stream>>>(
        z, out + (size_t)NT * 64, cs, wsf, wsi, partial, out, NT, K);
    vq_final<<<(KD + 255) / 256, 256, 0, stream>>>(cs, ema, wsf, wsi, partial,
                                                   out, NT, K, S);
}

// Round 5
// 247.556 us; speedup vs baseline: 2.1867x; 1.5447x over previous
//
#include <hip/hip_runtime.h>
#include <hip/hip_bf16.h>

// VectorQuantizer on MI355X — R12:
//  (a) cooperative coalesced fp64 refine in vq_main (unchanged since R9).
//  (b) dw: DIMENSION-partitioned dense scatter. Block (chunk,g) owns dim slice
//      [g*16,g*16+16) of ALL K codes: LDS acc = K x 16 f32 (64KB). Every lane
//      handles one (token,dim) pair per step: coalesced dword z load +
//      broadcast idx load + one ds_add. NO ballot/ffs/shfl chains — R9/R10/R11
//      proved those run ~15x over roofline regardless of block structure
//      (180-250us with VALUBusy 1-5%). No passes, no masked waste: z read
//      once, idx 4x. Exclusive partials at disjoint dim offsets (no global
//      atomics, no pre-zero); vq_final sums the chunk copies.
// Inputs (fp32): z[NT,64], codebook[K,64], cluster_size[K], ema_w[K,64]
// d_out (fp32): quantized[NT*64] | indices[NT] | loss[1] | new_codebook[K*64] |
//   new_cluster_size[K] | new_ema_w[K*64]
// ws dwords: cnt[K](int) | cnormp[K] | loss | n | partial[nchunks][K*64]

#define DECAY 0.99f
#define OMD   0.01f
#define EPSV  1e-5f
#define BIASF 192.0f    // folded into MFMA acc init: score' = 192 + z.c - |c|^2/2 > 0

typedef __attribute__((ext_vector_type(8))) __bf16 bf16x8;
typedef __attribute__((ext_vector_type(4))) float  float4v;

static __device__ __forceinline__ unsigned short bfbits(float f) {
    __bf16 h = (__bf16)f;
    return __builtin_bit_cast(unsigned short, h);
}
static __device__ __forceinline__ bf16x8 cvt8(float4v a, float4v b) {
    bf16x8 r;
    r[0] = (__bf16)a[0]; r[1] = (__bf16)a[1]; r[2] = (__bf16)a[2]; r[3] = (__bf16)a[3];
    r[4] = (__bf16)b[0]; r[5] = (__bf16)b[1]; r[6] = (__bf16)b[2]; r[7] = (__bf16)b[3];
    return r;
}

// key low 8 bits = per-lane candidate number iter = (c<<6)|(t<<2)|r
static __device__ __forceinline__ int dec_idx(unsigned key, int quad) {
    int iter = key & 255;
    return ((iter >> 6) << 8) + (((iter >> 2) & 15) << 4) + (quad << 2) + (iter & 3);
}

__global__ void vq_prep(const float* __restrict__ cb,
                        float* __restrict__ wsf, int* __restrict__ wsi,
                        int K, int NT) {
    int t = blockIdx.x * 256 + threadIdx.x;
    if (t < K) {
        wsi[t] = 0;                               // cnt
        const float4v* cp = (const float4v*)(cb + (size_t)t * 64);
        float s = 0.f;
        #pragma unroll
        for (int i = 0; i < 16; ++i) {
            float4v v = cp[i];
            s += v[0] * v[0] + v[1] * v[1] + v[2] * v[2] + v[3] * v[3];
        }
        wsf[K + t] = BIASF - 0.5f * s;            // cnormp
    }
    if (t == 0) wsf[2 * K] = 0.f;                 // loss
}

// 512 threads = 8 waves; 256 tokens/block (32/wave); codebook bf16 in LDS.
__launch_bounds__(512)
__global__ void vq_main(const float* __restrict__ z,
                        const float* __restrict__ cb,
                        float* __restrict__ wsf, int* __restrict__ wsi,
                        float* __restrict__ out,
                        int NT, int K) {
    __shared__ __align__(16) unsigned short cbs[256 * 72];   // 36 KB
    __shared__ float cns[256];
    __shared__ int hist[1024];

    const int tid  = threadIdx.x;
    const int lane = tid & 63;
    const int wave = tid >> 6;
    const int col  = lane & 15;
    const int quad = lane >> 4;
    const int wtok0 = blockIdx.x * 256 + wave * 32;
    const float* cnormp = wsf + K;
    float* lossp = wsf + 2 * K;
    const bool smallK = (K <= 1024);

    for (int i = tid; i < 1024; i += 512) hist[i] = 0;

    bf16x8 bf0[2], bf1[2];
    #pragma unroll
    for (int g = 0; g < 2; ++g) {
        int tok = wtok0 + g * 16 + col;
        if (tok >= NT) tok = NT - 1;
        const float* zp = z + (size_t)tok * 64 + quad * 8;
        float4v f0 = *(const float4v*)(zp);
        float4v f1 = *(const float4v*)(zp + 4);
        float4v f2 = *(const float4v*)(zp + 32);
        float4v f3 = *(const float4v*)(zp + 36);
        bf0[g] = cvt8(f0, f1);
        bf1[g] = cvt8(f2, f3);
    }

    unsigned k1[2] = { 0u, 0u }, k2[2] = { 0u, 0u };
    const unsigned kmask = 0xFFFFFF00u;
    const int nchunk = (K + 255) >> 8;

    for (int c = 0; c < nchunk; ++c) {
        #pragma unroll
        for (int i = 0; i < 8; ++i) {
            int f4 = (i * 512 + tid) * 4;
            int row = f4 >> 6, d = f4 & 63;
            int code = c * 256 + row;
            uint2 p;
            if (code < K) {
                float4v v = *(const float4v*)(cb + (size_t)code * 64 + d);
                p.x = (unsigned int)bfbits(v[0]) | ((unsigned int)bfbits(v[1]) << 16);
                p.y = (unsigned int)bfbits(v[2]) | ((unsigned int)bfbits(v[3]) << 16);
            } else { p.x = 0u; p.y = 0u; }
            *(uint2*)(&cbs[row * 72 + d]) = p;
        }
        if (tid < 256) {
            int code = c * 256 + tid;
            cns[tid] = (code < K) ? cnormp[code] : 0.0f;
        }
        __syncthreads();

        #pragma unroll 4
        for (int t = 0; t < 16; ++t) {
            const unsigned short* arow = cbs + (t * 16 + col) * 72;
            bf16x8 a0 = *(const bf16x8*)(arow + quad * 8);
            bf16x8 a1 = *(const bf16x8*)(arow + 32 + quad * 8);
            float4v cni = *(const float4v*)(cns + t * 16 + quad * 4);
            const int iterbase = (c << 6) | (t << 2);
            #pragma unroll
            for (int g = 0; g < 2; ++g) {
                float4v acc = cni;              // = BIAS - |c|^2/2
                acc = __builtin_amdgcn_mfma_f32_16x16x32_bf16(a0, bf0[g], acc, 0, 0, 0);
                acc = __builtin_amdgcn_mfma_f32_16x16x32_bf16(a1, bf1[g], acc, 0, 0, 0);
                #pragma unroll
                for (int r = 0; r < 4; ++r) {
                    unsigned kb = (__float_as_uint(acc[r]) & kmask) | (unsigned)(iterbase + r);
                    unsigned lo = k2[g] > kb ? k2[g] : kb;
                    k2[g] = k1[g] < lo ? k1[g] : lo;
                    k1[g] = k1[g] > kb ? k1[g] : kb;
                }
            }
        }
        __syncthreads();
    }

    // Cooperative exact refine (R9): 4 quad-lanes per token jointly rerank the
    // token's 8 candidates in fp64; each lane covers a 16-dim slice.
    int ibst[2];
    #pragma unroll
    for (int g = 0; g < 2; ++g) {
        int tok = wtok0 + g * 16 + col;
        if (tok >= NT) tok = NT - 1;
        int ia = dec_idx(k1[g], quad);
        int ib = dec_idx(k2[g], quad);
        int cand[8];
        #pragma unroll
        for (int q = 0; q < 4; ++q) {
            cand[2 * q]     = __shfl(ia, q * 16 + col, 64);
            cand[2 * q + 1] = __shfl(ib, q * 16 + col, 64);
        }
        const float* zr = z + (size_t)tok * 64 + quad * 16;
        float4v zv0 = *(const float4v*)(zr);
        float4v zv1 = *(const float4v*)(zr + 4);
        float4v zv2 = *(const float4v*)(zr + 8);
        float4v zv3 = *(const float4v*)(zr + 12);
        double ps[8];
        #pragma unroll
        for (int s = 0; s < 8; ++s) {
            int cc = (cand[s] < K) ? cand[s] : 0;
            const float* cr = cb + (size_t)cc * 64 + quad * 16;
            float4v c0 = *(const float4v*)(cr);
            float4v c1 = *(const float4v*)(cr + 4);
            float4v c2 = *(const float4v*)(cr + 8);
            float4v c3 = *(const float4v*)(cr + 12);
            double a = 0.0;
            #pragma unroll
            for (int j = 0; j < 4; ++j) {
                double e0 = (double)zv0[j] - (double)c0[j];
                double e1 = (double)zv1[j] - (double)c1[j];
                double e2 = (double)zv2[j] - (double)c2[j];
                double e3 = (double)zv3[j] - (double)c3[j];
                a = fma(e0, e0, a); a = fma(e1, e1, a);
                a = fma(e2, e2, a); a = fma(e3, e3, a);
            }
            ps[s] = (cand[s] < K) ? a : 1.0e300;
        }
        #pragma unroll
        for (int s = 0; s < 8; ++s) {
            ps[s] += __shfl_xor(ps[s], 16, 64);
            ps[s] += __shfl_xor(ps[s], 32, 64);
        }
        double bs = ps[0]; int bi = cand[0];
        #pragma unroll
        for (int s = 1; s < 8; ++s) {
            if (ps[s] < bs || (ps[s] == bs && cand[s] < bi)) { bs = ps[s]; bi = cand[s]; }
        }
        ibst[g] = bi;
    }

    const size_t off_idx = (size_t)NT * 64;

    if (lane < 32) {
        int tk = wtok0 + lane;
        if (tk < NT) {
            int ib = (lane < 16) ? ibst[0] : ibst[1];
            out[off_idx + tk] = (float)ib;
            if (smallK) atomicAdd(&hist[ib], 1);
            else        atomicAdd(&wsi[ib], 1);
        }
    }

    // Epilogue: quantized write + commitment loss.
    float lsum = 0.f;
    #pragma unroll
    for (int i = 0; i < 8; ++i) {
        int tw  = i * 4 + quad;
        int g   = i >> 2;
        int idx = __shfl(ibst[g], tw & 15, 64);
        int token = wtok0 + tw;
        if (token < NT) {
            int d4 = col * 4;
            float4v zf = *(const float4v*)(z  + (size_t)token * 64 + d4);
            float4v qf = *(const float4v*)(cb + (size_t)idx   * 64 + d4);
            *(float4v*)(out + (size_t)token * 64 + d4) = qf;
            float e0 = zf[0] - qf[0], e1 = zf[1] - qf[1];
            float e2 = zf[2] - qf[2], e3 = zf[3] - qf[3];
            lsum += e0 * e0 + e1 * e1 + e2 * e2 + e3 * e3;
        }
    }
    #pragma unroll
    for (int off = 1; off < 64; off <<= 1) lsum += __shfl_xor(lsum, off, 64);
    if (lane == 0) atomicAdd(lossp, lsum);

    __syncthreads();
    if (smallK) {
        for (int k = tid; k < K; k += 512) {
            int c = hist[k];
            if (c) atomicAdd(&wsi[k], c);
        }
    }
}

// Dimension-partitioned dw scatter. Block (chunk, g) owns dims [g*16,g*16+16)
// of ALL K codes; LDS acc[K][16] (64KB). Lane (tsub,d)=(lane>>4,lane&15):
// per step, one coalesced dword z load (4 tokens x 64B segments), one
// broadcast idx load, one ds_add into acc[code*16+d] (<=4-way banks).
// Fully dense — no ballot/shfl chains, no passes. Exclusive writeout to
// partial[chunk] at disjoint dim offsets. Block 0 folds the nsum duty.
__launch_bounds__(512)
__global__ void vq_dwred(const float* __restrict__ z,
                         const float* __restrict__ out_idx,
                         const float* __restrict__ cs,
                         float* __restrict__ wsf, const int* __restrict__ wsi,
                         float* __restrict__ partial,
                         float* __restrict__ out,
                         int NT, int K, int nchunks) {
    extern __shared__ float acc[];               // K*16 floats
    __shared__ float red[8];

    const int tid   = threadIdx.x;
    const int lane  = tid & 63;
    const int wave  = tid >> 6;                  // 8 waves
    const int chunk = blockIdx.x >> 2;
    const int g     = blockIdx.x & 3;
    const int tsub  = lane >> 4;
    const int d     = lane & 15;
    const size_t KD = (size_t)K * 64;

    for (int i = tid; i < K * 16; i += 512) acc[i] = 0.f;

    if (blockIdx.x == 0) {
        // folded nsum duty (cnt ready: vq_main completed before this kernel)
        float part = 0.f;
        for (int k = tid; k < K; k += 512)
            part += DECAY * cs[k] + OMD * (float)wsi[k];
        #pragma unroll
        for (int off = 1; off < 64; off <<= 1) part += __shfl_xor(part, off, 64);
        if (lane == 0) red[wave] = part;
        __syncthreads();
        if (tid == 0) {
            float nn = 0.f;
            #pragma unroll
            for (int i = 0; i < 8; ++i) nn += red[i];
            wsf[2 * K + 1] = nn;                                  // n
            out[(size_t)NT * 64 + NT] = wsf[2 * K] / ((float)NT * 64.0f);
        }
    }
    __syncthreads();

    const int C  = (NT + nchunks - 1) / nchunks;
    const int T0 = chunk * C;
    const int T1 = (T0 + C < NT) ? (T0 + C) : NT;
    const float* zs = z + g * 16 + d;

    #pragma unroll 4
    for (int t = T0 + wave * 4 + tsub; t < T1; t += 32) {
        float v   = zs[(size_t)t * 64];
        int  code = (int)out_idx[t];
        atomicAdd(&acc[code * 16 + d], v);
    }
    __syncthreads();

    // exclusive writeout: dims [g*16, g*16+16) of partial[chunk]
    float* pb = partial + (size_t)chunk * KD + g * 16;
    for (int i = tid; i < K * 16; i += 512) {
        int k = i >> 4, dd = i & 15;
        pb[(size_t)k * 64 + dd] = acc[i];
    }
}

// Final: sum chunk partials -> new_ema_w, new_codebook, new_cluster_size.
__global__ void vq_final(const float* __restrict__ cs,
                         const float* __restrict__ ema,
                         const float* __restrict__ wsf,
                         const int* __restrict__ wsi,
                         const float* __restrict__ partial,
                         float* __restrict__ out, int NT, int K, int S) {
    const int KD = K * 64;
    int t = blockIdx.x * 256 + threadIdx.x;
    if (t >= KD) return;
    const int k = t >> 6;
    const float n = wsf[2 * K + 1];
    float dsum = 0.f;
    #pragma unroll 4
    for (int s = 0; s < S; ++s) dsum += partial[(size_t)s * KD + t];
    const float dw = DECAY * ema[t] + OMD * dsum;
    const float ncs = DECAY * cs[k] + OMD * (float)wsi[k];
    const float csn = (ncs + EPSV) / (n + (float)K * EPSV) * n;
    const size_t off_cb  = (size_t)NT * 64 + NT + 1;
    const size_t off_cs  = off_cb + (size_t)KD;
    const size_t off_ema = off_cs + K;
    out[off_cb  + t] = dw / csn;
    out[off_ema + t] = dw;
    if ((t & 63) == 0) out[off_cs + k] = ncs;
}

extern "C" void kernel_launch(void* const* d_in, const int* in_sizes, int n_in,
                              void* d_out, int out_size, void* d_ws, size_t ws_size,
                              hipStream_t stream) {
    const float* z   = (const float*)d_in[0];
    const float* cb  = (const float*)d_in[1];
    const float* cs  = (const float*)d_in[2];
    const float* ema = (const float*)d_in[3];
    float* out = (float*)d_out;
    float* wsf = (float*)d_ws;
    int*   wsi = (int*)d_ws;

    const int NT = in_sizes[0] / 64;
    const int K  = in_sizes[2];
    const int KD = K * 64;

    // Chunk count: as many as workspace holds (partials), max 128.
    size_t avail = ws_size / 4;                  // dwords
    int nchunks = 128;
    while (nchunks > 1 && (size_t)2 * K + 2 + (size_t)nchunks * KD > avail)
        nchunks >>= 1;

    float* partial = wsf + 2 * K + 2;
    const size_t dwlds = (size_t)K * 16 * sizeof(float);   // 64KB @ K=1024

    vq_prep<<<(K + 255) / 256, 256, 0, stream>>>(cb, wsf, wsi, K, NT);
    vq_main<<<(NT + 255) / 256, 512, 0, stream>>>(z, cb, wsf, wsi, out, NT, K);
    vq_dwred<<<nchunks * 4, 512, dwlds, stream>>>(
        z, out + (size_t)NT * 64, cs, wsf, wsi, partial, out, NT, K, nchunks);
    vq_final<<<(KD + 255) / 256, 256, 0, stream>>>(cs, ema, wsf, wsi, partial,
                                                   out, NT, K, nchunks);
}